// Round 4
// baseline (58.398 us; speedup 1.0000x reference)
//
#include <hip/hip_runtime.h>
#include <hip/hip_bf16.h>
#include <math.h>

// Problem constants
#define B_   64
#define N_   256
#define DV_  2048
#define DP_  8
#define DT_  768
#define DF_  512
#define DK_  2056   // DV + DP

// Workspace layout (floats):
#define WS_WT 0        // wT[DF][B]  = 32768
#define WS_S  32768    // S[B][DP]   = 512
#define WS_C  33280    // c[B]       = 64
#define WS_V  33344    // v[B][DK]   = 131584

// ---------------------------------------------------------------------------
// Kernel A: w[b,f] = gelu(text[b,0,:]@Wt + bt)[f] * Wa[f], stored wT[f][b].
// grid = 256: bq = blk>>5 (8 groups of 8 b), fg = blk&31 (32 groups of 16 f).
// 8 batches share every Wt float4 load -> 12 MB total Wt traffic.
// Thread: fq = t&3 (f-quad), kc = t>>2 (64 chunks of 12 k).
// S[b] (position column sums) computed by fg==0 blocks.
// ---------------------------------------------------------------------------
__global__ __launch_bounds__(256) void kA(
    const float* __restrict__ pos,   // [B][N][DP]
    const float* __restrict__ text,  // [B][N][DT]
    const float* __restrict__ Wt,    // [DT][DF]
    const float* __restrict__ bt,    // [DF]
    const float* __restrict__ Wa,    // [DF]
    float* __restrict__ wT,          // [DF][B]
    float* __restrict__ S)           // [B][DP]
{
    const int bq = blockIdx.x >> 5;
    const int fg = blockIdx.x & 31;
    const int t  = threadIdx.x;

    __shared__ float  tx[8][DT_];        // 24 KB
    __shared__ float4 sred[8][4][64];    // 32 KB  [bb][fq][kc]
    __shared__ float4 sred2[8][4][9];    // 4.5 KB (padded: 9)
    __shared__ float  spos[8][4][DP_];   // 1 KB

    // stage text[b,0,:] for 8 batches (1536 float4)
    {
        const float4* base = (const float4*)text;
        #pragma unroll
        for (int r = 0; r < 6; ++r) {
            const int idx = t + 256 * r;          // 0..1535
            const int bb  = idx / 192;            // 192 float4 per row
            const int j   = idx - bb * 192;
            ((float4*)tx[bb])[j] = base[(size_t)(bq * 8 + bb) * (N_ * DT_ / 4) + j];
        }
    }

    // position column sums (fg==0 blocks only)
    if (fg == 0) {
        const int bb = t >> 5, l = t & 31;
        const int d = l & 7, g4 = l >> 3;
        float s = 0.f;
        for (int i = g4; i < N_; i += 4)
            s += pos[(size_t)(bq * 8 + bb) * N_ * DP_ + i * DP_ + d];
        spos[bb][g4][d] = s;
    }
    __syncthreads();

    if (fg == 0 && t < 64) {
        const int bb = t >> 3, d = t & 7;
        S[(bq * 8 + bb) * DP_ + d] =
            spos[bb][0][d] + spos[bb][1][d] + spos[bb][2][d] + spos[bb][3][d];
    }

    // main partial dot: 12 k's, 4 f's, 8 b's per thread
    const int fq = t & 3;
    const int kc = t >> 2;
    const int f0 = fg * 16 + fq * 4;
    float4 acc[8];
    #pragma unroll
    for (int bb = 0; bb < 8; ++bb) acc[bb] = make_float4(0.f, 0.f, 0.f, 0.f);

    const int kbase = kc * 12;
    #pragma unroll 4
    for (int j = 0; j < 12; ++j) {
        const int k = kbase + j;
        const float4 wv = *(const float4*)(Wt + (size_t)k * DF_ + f0);
        #pragma unroll
        for (int bb = 0; bb < 8; ++bb) {
            const float x = tx[bb][k];
            acc[bb].x = fmaf(x, wv.x, acc[bb].x);
            acc[bb].y = fmaf(x, wv.y, acc[bb].y);
            acc[bb].z = fmaf(x, wv.z, acc[bb].z);
            acc[bb].w = fmaf(x, wv.w, acc[bb].w);
        }
    }
    #pragma unroll
    for (int bb = 0; bb < 8; ++bb) sred[bb][fq][kc] = acc[bb];
    __syncthreads();

    // phase-1 reduce: 32 (bb,fq) combos x 8 threads each; consecutive-kc reads
    {
        const int combo = t >> 3, rt = t & 7;
        const int bb = combo >> 2, fq2 = combo & 3;
        float4 s = sred[bb][fq2][rt];
        #pragma unroll
        for (int g = 1; g < 8; ++g) {
            const float4 p = sred[bb][fq2][g * 8 + rt];
            s.x += p.x; s.y += p.y; s.z += p.z; s.w += p.w;
        }
        sred2[bb][fq2][rt] = s;
    }
    __syncthreads();

    if (t < 32) {
        const int bb = t >> 2, fq2 = t & 3;
        float4 s = sred2[bb][fq2][0];
        #pragma unroll
        for (int g = 1; g < 8; ++g) {
            const float4 p = sred2[bb][fq2][g];
            s.x += p.x; s.y += p.y; s.z += p.z; s.w += p.w;
        }
        const float sv[4] = {s.x, s.y, s.z, s.w};
        const int b = bq * 8 + bb;
        #pragma unroll
        for (int cc = 0; cc < 4; ++cc) {
            const int f = fg * 16 + fq2 * 4 + cc;
            const float z = sv[cc] + bt[f];
            const float ge = 0.5f * z * (1.f + erff(z * 0.70710678118654752f));
            wT[(size_t)f * B_ + b] = ge * Wa[f];
        }
    }
}

// ---------------------------------------------------------------------------
// Kernel B: v[b,k] = sum_f Wo[k,f]*w[b,f].  Blocks 0..513: 4 k-rows each
// (2 blocks/CU, 8 waves/CU). Block 514: c[b] = sum_f bo[f]*w[b,f] + ba.
// Thread map (main): bq = t&15 (4 b's via float4), fg = t>>4 (32-f chunk).
// ---------------------------------------------------------------------------
__global__ __launch_bounds__(256) void kB(
    const float* __restrict__ Wo,    // [DK][DF]
    const float* __restrict__ bo,    // [DF]
    const float* __restrict__ ba,    // [1]
    const float* __restrict__ wT,    // [DF][B]
    float* __restrict__ v,           // [B][DK]
    float* __restrict__ c)           // [B]
{
    const int t = threadIdx.x;
    __shared__ float  wo[4][DF_];       // 8 KB
    __shared__ float4 red[4][16][16];   // 16 KB
    __shared__ float  sbo[DF_];
    __shared__ float4 cred[16][16];

    if (blockIdx.x < 514) {
        const int k0 = blockIdx.x * 4;
        {
            const float4* src = (const float4*)(Wo + (size_t)k0 * DF_);
            float4*       dst = (float4*)wo;
            dst[t]       = src[t];
            dst[t + 256] = src[t + 256];
        }
        __syncthreads();

        const int bq = t & 15;
        const int fg = t >> 4;
        float4 acc0 = make_float4(0.f, 0.f, 0.f, 0.f);
        float4 acc1 = acc0, acc2 = acc0, acc3 = acc0;
        const int fbase = fg * 32;
        #pragma unroll 4
        for (int j = 0; j < 32; ++j) {
            const int f = fbase + j;
            const float4 wv = *(const float4*)(wT + (size_t)f * B_ + 4 * bq);
            const float s0 = wo[0][f], s1 = wo[1][f], s2 = wo[2][f], s3 = wo[3][f];
            acc0.x = fmaf(s0, wv.x, acc0.x); acc0.y = fmaf(s0, wv.y, acc0.y);
            acc0.z = fmaf(s0, wv.z, acc0.z); acc0.w = fmaf(s0, wv.w, acc0.w);
            acc1.x = fmaf(s1, wv.x, acc1.x); acc1.y = fmaf(s1, wv.y, acc1.y);
            acc1.z = fmaf(s1, wv.z, acc1.z); acc1.w = fmaf(s1, wv.w, acc1.w);
            acc2.x = fmaf(s2, wv.x, acc2.x); acc2.y = fmaf(s2, wv.y, acc2.y);
            acc2.z = fmaf(s2, wv.z, acc2.z); acc2.w = fmaf(s2, wv.w, acc2.w);
            acc3.x = fmaf(s3, wv.x, acc3.x); acc3.y = fmaf(s3, wv.y, acc3.y);
            acc3.z = fmaf(s3, wv.z, acc3.z); acc3.w = fmaf(s3, wv.w, acc3.w);
        }
        red[0][fg][bq] = acc0;
        red[1][fg][bq] = acc1;
        red[2][fg][bq] = acc2;
        red[3][fg][bq] = acc3;
        __syncthreads();
        if (t < 64) {
            const int r = t >> 4, bq2 = t & 15;
            float4 s = red[r][0][bq2];
            #pragma unroll
            for (int g = 1; g < 16; ++g) {
                const float4 p = red[r][g][bq2];
                s.x += p.x; s.y += p.y; s.z += p.z; s.w += p.w;
            }
            const float sv[4] = {s.x, s.y, s.z, s.w};
            #pragma unroll
            for (int cc = 0; cc < 4; ++cc)
                v[(size_t)(4 * bq2 + cc) * DK_ + k0 + r] = sv[cc];
        }
    } else {
        for (int k = t; k < DF_; k += 256) sbo[k] = bo[k];
        __syncthreads();
        const int bq = t & 15;
        const int fh = t >> 4;
        float4 acc = make_float4(0.f, 0.f, 0.f, 0.f);
        for (int j = 0; j < 32; ++j) {
            const int f = fh * 32 + j;
            const float s = sbo[f];
            const float4 wv = *(const float4*)(wT + (size_t)f * B_ + 4 * bq);
            acc.x = fmaf(s, wv.x, acc.x);
            acc.y = fmaf(s, wv.y, acc.y);
            acc.z = fmaf(s, wv.z, acc.z);
            acc.w = fmaf(s, wv.w, acc.w);
        }
        cred[fh][bq] = acc;
        __syncthreads();
        if (fh == 0) {
            float4 s = cred[0][bq];
            #pragma unroll
            for (int h = 1; h < 16; ++h) {
                const float4 p = cred[h][bq];
                s.x += p.x; s.y += p.y; s.z += p.z; s.w += p.w;
            }
            const float sv[4] = {s.x, s.y, s.z, s.w};
            #pragma unroll
            for (int cc = 0; cc < 4; ++cc)
                c[4 * bq + cc] = sv[cc] + ba[0];
        }
    }
}

// ---------------------------------------------------------------------------
// Kernel C (bulk, HBM-bound): 16 rows per block (one b), v1[b] staged in LDS,
// per-row constants precomputed. Inner loop = pure visual float4 stream.
// grid = 1024 blocks (4/CU, 16 waves/CU), 4 rows per wave.
// out[b,i] = visual[b,i,:].v1[b] + 257*pos[b,i,:].v2[b] - S[b].v2[b] + c[b]
// ---------------------------------------------------------------------------
__global__ __launch_bounds__(256) void kC(
    const float* __restrict__ visual, // [B][N][DV]
    const float* __restrict__ pos,    // [B][N][DP]
    const float* __restrict__ v,      // [B][DK]
    const float* __restrict__ S,      // [B][DP]
    const float* __restrict__ c,      // [B]
    float* __restrict__ out)          // [B][N]
{
    const int t    = threadIdx.x;
    const int wave = t >> 6;
    const int lane = t & 63;
    const int b    = blockIdx.x >> 4;
    const int i0   = (blockIdx.x & 15) << 4;   // 16 rows per block

    __shared__ float sv[DV_];   // 8 KB: v1[b]
    __shared__ float rc[16];    // per-row constant

    {
        const float4* src = (const float4*)(v + (size_t)b * DK_);
        float4* dst = (float4*)sv;
        dst[t]       = src[t];
        dst[t + 256] = src[t + 256];
    }
    if (t < 16) {
        const float* v2 = v + (size_t)b * DK_ + DV_;
        const float* pr = pos + ((size_t)b * N_ + i0 + t) * DP_;
        const float* Sb = S + b * DP_;
        float pd = 0.f, sd = 0.f;
        #pragma unroll
        for (int d = 0; d < DP_; ++d) {
            pd = fmaf(pr[d], v2[d], pd);
            sd = fmaf(Sb[d], v2[d], sd);
        }
        rc[t] = 257.f * pd - sd + c[b];
    }
    __syncthreads();

    const int r0 = i0 + wave * 4;
    const float4* v0  = (const float4*)(visual + ((size_t)b * N_ + r0) * DV_);
    const float4* svb = (const float4*)sv;

    float a0 = 0.f, a1 = 0.f, a2 = 0.f, a3 = 0.f;
    #pragma unroll
    for (int j = 0; j < 8; ++j) {
        const int idx = lane + 64 * j;
        const float4 wv = svb[idx];
        const float4 x0 = v0[idx];
        const float4 x1 = v0[idx + 512];
        const float4 x2 = v0[idx + 1024];
        const float4 x3 = v0[idx + 1536];
        a0 = fmaf(x0.x, wv.x, a0); a0 = fmaf(x0.y, wv.y, a0);
        a0 = fmaf(x0.z, wv.z, a0); a0 = fmaf(x0.w, wv.w, a0);
        a1 = fmaf(x1.x, wv.x, a1); a1 = fmaf(x1.y, wv.y, a1);
        a1 = fmaf(x1.z, wv.z, a1); a1 = fmaf(x1.w, wv.w, a1);
        a2 = fmaf(x2.x, wv.x, a2); a2 = fmaf(x2.y, wv.y, a2);
        a2 = fmaf(x2.z, wv.z, a2); a2 = fmaf(x2.w, wv.w, a2);
        a3 = fmaf(x3.x, wv.x, a3); a3 = fmaf(x3.y, wv.y, a3);
        a3 = fmaf(x3.z, wv.z, a3); a3 = fmaf(x3.w, wv.w, a3);
    }
    #pragma unroll
    for (int off = 1; off < 64; off <<= 1) {
        a0 += __shfl_xor(a0, off, 64);
        a1 += __shfl_xor(a1, off, 64);
        a2 += __shfl_xor(a2, off, 64);
        a3 += __shfl_xor(a3, off, 64);
    }

    if (lane < 4) {
        const float accq = (lane == 0) ? a0 : (lane == 1) ? a1 : (lane == 2) ? a2 : a3;
        out[(size_t)b * N_ + r0 + lane] = accq + rc[wave * 4 + lane];
    }
}

// ---------------------------------------------------------------------------
extern "C" void kernel_launch(void* const* d_in, const int* in_sizes, int n_in,
                              void* d_out, int out_size, void* d_ws, size_t ws_size,
                              hipStream_t stream) {
    const float* visual   = (const float*)d_in[0];
    const float* position = (const float*)d_in[1];
    const float* text     = (const float*)d_in[2];
    const float* Wt       = (const float*)d_in[3];
    const float* bt       = (const float*)d_in[4];
    const float* Wo       = (const float*)d_in[5];
    const float* bo       = (const float*)d_in[6];
    const float* Wa       = (const float*)d_in[7];
    const float* ba       = (const float*)d_in[8];
    float* out = (float*)d_out;

    float* ws = (float*)d_ws;
    float* wT = ws + WS_WT;
    float* S  = ws + WS_S;
    float* c  = ws + WS_C;
    float* v  = ws + WS_V;

    kA<<<256, 256, 0, stream>>>(position, text, Wt, bt, Wa, wT, S);
    kB<<<515, 256, 0, stream>>>(Wo, bo, ba, wT, v, c);
    kC<<<1024, 256, 0, stream>>>(visual, position, v, S, c, out);
}